// Round 2
// baseline (1252.839 us; speedup 1.0000x reference)
//
#include <hip/hip_runtime.h>
#include <math.h>

#define DIM_ 2048
#define KTOP 8
#define MSLOT 16
#define TSTEPS 256
#define NB 64
#define NTHREADS 320 // 5 waves: wave0 = serial wave, waves 1..4 = workers
#define NWORK 256
#define EPT 8
#define CCAP 128

static_assert(NWORK * EPT == DIM_, "mapping");

#define DPP0(src, ctrl, rm) __builtin_amdgcn_update_dpp(0, (src), (ctrl), (rm), 0xf, true)

// ---- f64 packed-key helpers (key = f32bits(|c|) : ~index, never NaN) ----
__device__ __forceinline__ void ced(double &a, double &b) {
  double mx = fmax(a, b);
  b = fmin(a, b);
  a = mx;
}

// merge own sorted-2 (k[0..1]) with partner's sorted-2 -> sorted-4 in k[0..3]
template <int CTRL, int RM>
__device__ __forceinline__ void merge_2to4_d(double k[8]) {
  int lo0 = DPP0(__double2loint(k[0]), CTRL, RM);
  int hi0 = DPP0(__double2hiint(k[0]), CTRL, RM);
  int lo1 = DPP0(__double2loint(k[1]), CTRL, RM);
  int hi1 = DPP0(__double2hiint(k[1]), CTRL, RM);
  double b0 = __hiloint2double(hi0, lo0);
  double b1 = __hiloint2double(hi1, lo1);
  double z2 = b1, z3 = b0; // bitonic: [k0,k1,b1,b0]
  ced(k[0], z2); ced(k[1], z3);
  ced(k[0], k[1]); ced(z2, z3);
  k[2] = z2; k[3] = z3;
}

// merge own sorted-4 (k[0..3]) with partner's sorted-4 -> sorted-8
template <int CTRL, int RM>
__device__ __forceinline__ void merge_first4(double k[8]) {
  double b[4];
#pragma unroll
  for (int i = 0; i < 4; i++) {
    int lo = DPP0(__double2loint(k[i]), CTRL, RM);
    int hi = DPP0(__double2hiint(k[i]), CTRL, RM);
    b[i] = __hiloint2double(hi, lo);
  }
  k[4] = b[3]; k[5] = b[2]; k[6] = b[1]; k[7] = b[0]; // bitonic sequence
  ced(k[0],k[4]); ced(k[1],k[5]); ced(k[2],k[6]); ced(k[3],k[7]);
  ced(k[0],k[2]); ced(k[1],k[3]); ced(k[4],k[6]); ced(k[5],k[7]);
  ced(k[0],k[1]); ced(k[2],k[3]); ced(k[4],k[5]); ced(k[6],k[7]);
}

// pull partner's sorted-8, keep top-8 of union, resort desc
template <int CTRL, int RM>
__device__ __forceinline__ void merge_level(double k[8]) {
  double b[8];
#pragma unroll
  for (int i = 0; i < 8; i++) {
    int lo = DPP0(__double2loint(k[i]), CTRL, RM);
    int hi = DPP0(__double2hiint(k[i]), CTRL, RM);
    b[i] = __hiloint2double(hi, lo);
  }
#pragma unroll
  for (int i = 0; i < 8; i++) k[i] = fmax(k[i], b[7 - i]);
  ced(k[0],k[4]); ced(k[1],k[5]); ced(k[2],k[6]); ced(k[3],k[7]);
  ced(k[0],k[2]); ced(k[1],k[3]); ced(k[4],k[6]); ced(k[5],k[7]);
  ced(k[0],k[1]); ced(k[2],k[3]); ced(k[4],k[5]); ced(k[6],k[7]);
}

// ---- f32 list network (for theta = 8th largest of 256 lane maxima) ----
__device__ __forceinline__ void cedf(float &a, float &b) {
  float mx = fmaxf(a, b);
  b = fminf(a, b);
  a = mx;
}
__device__ __forceinline__ void sort4f(float k[8]) {
  cedf(k[0],k[1]); cedf(k[2],k[3]);
  cedf(k[0],k[2]); cedf(k[1],k[3]);
  cedf(k[1],k[2]);
}
template <int CTRL, int RM>
__device__ __forceinline__ void merge_first4_f32(float k[8]) {
  float b[4];
#pragma unroll
  for (int i = 0; i < 4; i++)
    b[i] = __int_as_float(DPP0(__float_as_int(k[i]), CTRL, RM));
  k[4] = b[3]; k[5] = b[2]; k[6] = b[1]; k[7] = b[0];
  cedf(k[0],k[4]); cedf(k[1],k[5]); cedf(k[2],k[6]); cedf(k[3],k[7]);
  cedf(k[0],k[2]); cedf(k[1],k[3]); cedf(k[4],k[6]); cedf(k[5],k[7]);
  cedf(k[0],k[1]); cedf(k[2],k[3]); cedf(k[4],k[5]); cedf(k[6],k[7]);
}
template <int CTRL, int RM>
__device__ __forceinline__ void merge_level_f32(float k[8]) {
  float b[8];
#pragma unroll
  for (int i = 0; i < 8; i++)
    b[i] = __int_as_float(DPP0(__float_as_int(k[i]), CTRL, RM));
#pragma unroll
  for (int i = 0; i < 8; i++) k[i] = fmaxf(k[i], b[7 - i]);
  cedf(k[0],k[4]); cedf(k[1],k[5]); cedf(k[2],k[6]); cedf(k[3],k[7]);
  cedf(k[0],k[2]); cedf(k[1],k[3]); cedf(k[4],k[6]); cedf(k[5],k[7]);
  cedf(k[0],k[1]); cedf(k[2],k[3]); cedf(k[4],k[5]); cedf(k[6],k[7]);
}

#define FMAX_STAGE(x, ctrl, rm)                                                \
  x = fmaxf(x, __int_as_float(DPP0(__float_as_int(x), ctrl, rm)))
#define FADD_STAGE(x, ctrl, rm)                                                \
  x = x + __int_as_float(DPP0(__float_as_int(x), ctrl, rm))

__device__ __forceinline__ float wave_max_f32(float x) {
  FMAX_STAGE(x, 0x111, 0xf);
  FMAX_STAGE(x, 0x112, 0xf);
  FMAX_STAGE(x, 0x114, 0xf);
  FMAX_STAGE(x, 0x118, 0xf);
  FMAX_STAGE(x, 0x142, 0xa);
  FMAX_STAGE(x, 0x143, 0xc);
  return x; // lane 63 has the max
}
__device__ __forceinline__ float wave_sum_f32(float x) {
  FADD_STAGE(x, 0x111, 0xf);
  FADD_STAGE(x, 0x112, 0xf);
  FADD_STAGE(x, 0x114, 0xf);
  FADD_STAGE(x, 0x118, 0xf);
  FADD_STAGE(x, 0x142, 0xa);
  FADD_STAGE(x, 0x143, 0xc);
  return x; // lane 63 has the sum
}
__device__ __forceinline__ int rl63(int v) {
  return __builtin_amdgcn_readlane(v, 63);
}

__global__ void __launch_bounds__(NTHREADS)
me_fused(const float *__restrict__ x, const float *__restrict__ tape_re,
         const float *__restrict__ tape_im, const float *__restrict__ eta_param,
         const float *__restrict__ tbias_re, const float *__restrict__ tbias_im,
         float *__restrict__ out) {
  __shared__ float4 sc4[DIM_];                 // (h, vre, vim, 0)
  __shared__ float2 dxy[DIM_];                 // scatter deltas
  __shared__ float4 lmax4[NWORK / 4];          // 256 per-lane |c| maxima
  __shared__ unsigned long long cand_lds[CCAP];// candidate keys (f64 packed)
  __shared__ int ccnt;                         // candidate count
  __shared__ float red_sh[4];                  // norm^2 partials

  const int tid = threadIdx.x;
  const int lane = tid & 63;
  const int wid = tid >> 6;
  const int wtid = tid - 64; // worker element base (valid for wid>0)
  const int b = blockIdx.x;

  const float eta = fabsf(eta_param[0]);

  // worker state (unnormalized v; ivn applied per step)
  float vre[EPT], vim[EPT], tbre_[EPT], tbim_[EPT];
  float hcur[EPT], hnext[EPT], av[EPT];
  const float *xb = x + (size_t)b * TSTEPS * DIM_;

  if (wid > 0) {
    float acc = 0.f, lm = 0.f;
#pragma unroll
    for (int j = 0; j < EPT; j++) {
      int e = wtid + NWORK * j;
      float a = tape_re[e], c2 = tape_im[e];
      vre[j] = a; vim[j] = c2;
      tbre_[j] = tbias_re[e]; tbim_[j] = tbias_im[e];
      float h = xb[e];
      hcur[j] = h; hnext[j] = h;
      dxy[e] = make_float2(0.f, 0.f);
      acc += a * a + c2 * c2;
      // prep(0): scale-invariant key magnitude + staging
      float cr = h * a, ci = h * c2;
      av[j] = sqrtf(cr * cr + ci * ci);
      lm = fmaxf(lm, av[j]);
      sc4[e] = make_float4(h, a, c2, 0.f);
    }
    float ws = wave_sum_f32(acc);
    if (lane == 63) red_sh[wid - 1] = ws;
    ((float *)lmax4)[wtid] = lm;
  }
  if (tid == 0) ccnt = 0;

  // transient slots live in wave0 registers (lanes 0..15)
  int s_ti = 0, s_tj = 0, s_cnt = 0;
  float s_mre = 0.f, s_mim = 0.f;

  float osr[EPT], osi[EPT]; // workers: normalized s (pre-update), for patch

  __syncthreads(); // B1 for t=0

  for (int t = 0; t < TSTEPS; t++) {
    // per-step scalar: ivn = 1/max(||v||,1e-8)  (red_sh from prep/[C])
    float ivn;
    {
      float tot = (red_sh[0] + red_sh[1]) + (red_sh[2] + red_sh[3]);
      ivn = 1.f / fmaxf(sqrtf(tot), 1e-8f);
    }

    // ============ [E] workers: theta + candidate extraction + overlap ======
    if (wid > 0) {
      // issue global memory ops early (drained at B1b)
      if (t + 1 < TSTEPS) {
        const float *xr = xb + (size_t)(t + 1) * DIM_;
#pragma unroll
        for (int j = 0; j < EPT; j++) hnext[j] = xr[wtid + NWORK * j];
      }
      if (t > 0) {
        float *op = out + ((size_t)b * TSTEPS + (t - 1)) * DIM_;
#pragma unroll
        for (int j = 0; j < EPT; j++) {
          float sr = vre[j] * ivn, si = vim[j] * ivn;
          op[wtid + NWORK * j] = sqrtf(sr * sr + si * si);
        }
      }
      // theta = 8th largest of the 256 per-lane maxima (f32 network)
      float4 q = lmax4[lane];
      float k[8];
      k[0] = q.x; k[1] = q.y; k[2] = q.z; k[3] = q.w;
      k[4] = 0.f; k[5] = 0.f; k[6] = 0.f; k[7] = 0.f;
      sort4f(k);
      merge_first4_f32<0x111, 0xf>(k);
      merge_level_f32<0x112, 0xf>(k);
      merge_level_f32<0x114, 0xf>(k);
      merge_level_f32<0x118, 0xf>(k);
      merge_level_f32<0x142, 0xa>(k);
      merge_level_f32<0x143, 0xc>(k);
      float th = __int_as_float(rl63(__float_as_int(k[7])));
      // extract candidates (guaranteed: 8 <= cnt <= 64 mod exact f32 ties)
#pragma unroll
      for (int j = 0; j < EPT; j++) {
        if (av[j] >= th) {
          int e = wtid + NWORK * j;
          int slot = atomicAdd(&ccnt, 1);
          if (slot < CCAP)
            cand_lds[slot] = (unsigned long long)__double_as_longlong(
                __hiloint2double(__float_as_int(av[j]), ~e));
        }
      }
      // speculative update with delta = 0 (exact for untouched elements)
#pragma unroll
      for (int j = 0; j < EPT; j++) {
        float sri = vre[j] * ivn, sii2 = vim[j] * ivn;
        osr[j] = sri; osi[j] = sii2;
        float h = hcur[j];
        float car = h * sri, cai = h * sii2;
        bool res = (car > 1e-6f) && (fabsf(cai) < car);
        bool tor = (car < -1e-6f) || (fabsf(cai) >= fabsf(car));
        float m1 = (res || tor) ? 1.f : 0.f;
        float mt = tor ? 1.f : 0.f;
        float ur = eta * (car * m1 + mt * tbre_[j]);
        float ui = eta * (cai * m1 + mt * tbim_[j]);
        vre[j] = sri + ur; vim[j] = sii2 + ui;
      }
    }
    __syncthreads(); // B1b: candidates ready

    // ============ [S] wave0: sort candidates + serial dynamics =============
    if (wid == 0) {
      int cnt = ccnt;
      if (lane == 0) ccnt = 0; // reset for next step (next append after B2+B1)
      if (cnt > CCAP) cnt = CCAP;
      // load 2 candidates per lane: slots 2*lane, 2*lane+1
      unsigned long long u0 = cand_lds[2 * lane];
      unsigned long long u1 = cand_lds[2 * lane + 1];
      double a = (2 * lane < cnt) ? __longlong_as_double((long long)u0) : 0.0;
      double b2 = (2 * lane + 1 < cnt) ? __longlong_as_double((long long)u1) : 0.0;
      double c[8];
      c[0] = fmax(a, b2); c[1] = fmin(a, b2);
      c[2] = 0.0; c[3] = 0.0; c[4] = 0.0; c[5] = 0.0; c[6] = 0.0; c[7] = 0.0;
      merge_2to4_d<0x111, 0xf>(c);  // lanes pairs  -> sorted-4  (4 slots)
      merge_first4<0x112, 0xf>(c);  // -> sorted-8 covering 8 slots
      merge_level<0x114, 0xf>(c);   // 16 slots
      merge_level<0x118, 0xf>(c);   // lane15 = top-8 of slots 0..31
      int src = 15;
      if (cnt > 32) { merge_level<0x142, 0xa>(c); src = 31; } // slots 0..63
      if (cnt > 64) { merge_level<0x143, 0xc>(c); src = 63; } // slots 0..127
      int top[KTOP];
#pragma unroll
      for (int r = 0; r < KTOP; r++)
        top[r] = ~__builtin_amdgcn_readlane(__double2loint(c[r]), src);

      // ---- pair (ii,jj) for lane p, row-major triu order ----
      int pi = (lane < 28) ? lane : 27;
      int ii = 0, base = 0;
      if (pi >= 7)  { ii = 1; base = 7;  }
      if (pi >= 13) { ii = 2; base = 13; }
      if (pi >= 18) { ii = 3; base = 18; }
      if (pi >= 22) { ii = 4; base = 22; }
      if (pi >= 25) { ii = 5; base = 25; }
      if (pi >= 27) { ii = 6; base = 27; }
      int jj = ii + 1 + (pi - base);
      int gi = top[0];
      if (ii == 1) gi = top[1];
      if (ii == 2) gi = top[2];
      if (ii == 3) gi = top[3];
      if (ii == 4) gi = top[4];
      if (ii == 5) gi = top[5];
      if (ii == 6) gi = top[6];
      int gj = top[1];
      if (jj == 2) gj = top[2];
      if (jj == 3) gj = top[3];
      if (jj == 4) gj = top[4];
      if (jj == 5) gj = top[5];
      if (jj == 6) gj = top[6];
      if (jj == 7) gj = top[7];

      float4 c4i = sc4[gi], c4j = sc4[gj];
      float sri = c4i.y * ivn, sii2 = c4i.z * ivn;
      float srj = c4j.y * ivn, sij = c4j.z * ivn;
      float cri = c4i.x * sri, cii = c4i.x * sii2;
      float crj = c4j.x * srj, cij = c4j.x * sij;
      float score = cri * crj + cii * cij; // Re(c_i conj(c_j))
      bool valid = (lane < 28);
      bool pos = valid && (score > 0.f);
      unsigned long long posmask = __ballot(pos);
      int npos = __popcll(posmask);
      float pr = sri * srj - sii2 * sij;
      float pq = sri * sij + sii2 * srj;
      float ap = fmaxf(sqrtf(pr * pr + pq * pq), 1e-8f);
      float mr = (0.05f * pr) / ap, mi = (0.05f * pq) / ap;

      unsigned long long bmask = 0ull;
      if (npos > 0) {
        int nbind = (int)((float)npos * 0.15f);
        if (nbind < 1) nbind = 1;
        float val = pos ? score : -__builtin_inff();
        float th2 = 0.f;
        for (int k2 = 0; k2 < nbind; ++k2) {
          float mx = wave_max_f32(val);
          th2 = __int_as_float(rl63(__float_as_int(mx)));
          if (k2 + 1 < nbind) {
            unsigned long long em = __ballot(val == th2);
            if (lane == (int)__builtin_ctzll(em)) val = -__builtin_inff();
          }
        }
        bool bind = valid && (score >= th2);
        bmask = __ballot(bind);
      }
      // slot scan in pair order
      while (bmask) {
        int pp = (int)__builtin_ctzll(bmask);
        bmask &= bmask - 1;
        int pci = __builtin_amdgcn_readlane(gi, pp);
        int pcj = __builtin_amdgcn_readlane(gj, pp);
        int pmr = __builtin_amdgcn_readlane(__float_as_int(mr), pp);
        int pmi = __builtin_amdgcn_readlane(__float_as_int(mi), pp);
        bool isslot = (lane < MSLOT);
        bool match = isslot && (s_cnt > 0) &&
                     ((s_ti == pci && s_tj == pcj) ||
                      (s_ti == pcj && s_tj == pci));
        unsigned long long mm = __ballot(match);
        if (mm != 0ull) {
          if (lane == (int)__builtin_ctzll(mm)) s_cnt = 5; // refresh only
        } else {
          unsigned long long fm = __ballot(isslot && s_cnt <= 0);
          if (fm != 0ull && lane == (int)__builtin_ctzll(fm)) {
            s_ti = pci; s_tj = pcj;
            s_mre = __int_as_float(pmr); s_mim = __int_as_float(pmi);
            s_cnt = 5;
          }
        }
      }
      // decay + alive + scatter; dead slots add exact 0.0 -> skip atomics
      if (lane < MSLOT) {
        s_mre *= 0.9f; s_mim *= 0.9f; s_cnt -= 1;
        bool alive = (s_cnt > 0) &&
                     (sqrtf(s_mre * s_mre + s_mim * s_mim) > 1e-6f);
        if (!alive) { s_cnt = 0; s_mre = 0.f; s_mim = 0.f; }
        if (s_cnt > 0) {
          atomicAdd(&dxy[s_ti].x, 0.1f * s_mre);
          atomicAdd(&dxy[s_tj].x, 0.1f * s_mre);
          atomicAdd(&dxy[s_ti].y, 0.1f * s_mim);
          atomicAdd(&dxy[s_tj].y, 0.1f * s_mim);
        }
      }
    }
    __syncthreads(); // B2: dxy ready

    // ============ [C] workers: sparse patch + norm + prep(t+1) =============
    if (wid > 0) {
      float2 dd[EPT];
#pragma unroll
      for (int j = 0; j < EPT; j++) dd[j] = dxy[wtid + NWORK * j];
      float acc2 = 0.f, lm = 0.f;
#pragma unroll
      for (int j = 0; j < EPT; j++) {
        int e = wtid + NWORK * j;
        if (dd[j].x != 0.f || dd[j].y != 0.f) {
          dxy[e] = make_float2(0.f, 0.f); // re-zero touched
          float ar = osr[j] + dd[j].x, ai = osi[j] + dd[j].y;
          float h = hcur[j];
          float car = h * ar, cai = h * ai;
          bool res = (car > 1e-6f) && (fabsf(cai) < car);
          bool tor = (car < -1e-6f) || (fabsf(cai) >= fabsf(car));
          float m1 = (res || tor) ? 1.f : 0.f;
          float mt = tor ? 1.f : 0.f;
          float ur = eta * (car * m1 + mt * tbre_[j]);
          float ui = eta * (cai * m1 + mt * tbim_[j]);
          vre[j] = osr[j] + ur; vim[j] = osi[j] + ui;
        }
        acc2 += vre[j] * vre[j] + vim[j] * vim[j];
        // prep(t+1): advance h, compute |c| key magnitude, stage sc4
        float h = hnext[j];
        hcur[j] = h;
        float cr = h * vre[j], ci = h * vim[j];
        av[j] = sqrtf(cr * cr + ci * ci);
        lm = fmaxf(lm, av[j]);
        sc4[e] = make_float4(h, vre[j], vim[j], 0.f);
      }
      float ws = wave_sum_f32(acc2);
      if (lane == 63) red_sh[wid - 1] = ws;
      ((float *)lmax4)[wtid] = lm;
    }
    __syncthreads(); // B1(t+1): lmax/sc4/red_sh ready
  }

  // epilogue: final output row
  if (wid > 0) {
    float tot = (red_sh[0] + red_sh[1]) + (red_sh[2] + red_sh[3]);
    float ivnF = 1.f / fmaxf(sqrtf(tot), 1e-8f);
    float *op = out + ((size_t)b * TSTEPS + (TSTEPS - 1)) * DIM_;
#pragma unroll
    for (int j = 0; j < EPT; j++) {
      float sr = vre[j] * ivnF, si = vim[j] * ivnF;
      op[wtid + NWORK * j] = sqrtf(sr * sr + si * si);
    }
  }
}

extern "C" void kernel_launch(void *const *d_in, const int *in_sizes, int n_in,
                              void *d_out, int out_size, void *d_ws,
                              size_t ws_size, hipStream_t stream) {
  const float *x = (const float *)d_in[0];
  const float *tre = (const float *)d_in[1];
  const float *tim = (const float *)d_in[2];
  const float *eta = (const float *)d_in[3];
  const float *tbre = (const float *)d_in[4];
  const float *tbim = (const float *)d_in[5];
  float *out = (float *)d_out;
  me_fused<<<NB, NTHREADS, 0, stream>>>(x, tre, tim, eta, tbre, tbim, out);
}

// Round 3
// 1038.100 us; speedup vs baseline: 1.2069x; 1.2069x over previous
//
#include <hip/hip_runtime.h>
#include <math.h>

#define DIM_ 2048
#define KTOP 8
#define MSLOT 16
#define TSTEPS 256
#define NB 64
#define NTHREADS 320 // 5 waves: wave0 = serial wave, waves 1..4 = workers
#define NWORK 256
#define EPT 8
#define CCAP 128

static_assert(NWORK * EPT == DIM_, "mapping");

#define DPP0(src, ctrl, rm) __builtin_amdgcn_update_dpp(0, (src), (ctrl), (rm), 0xf, true)

// ---- f64 packed-key helpers (key = f32bits(|c|) : ~index, never NaN) ----
__device__ __forceinline__ void ced(double &a, double &b) {
  double mx = fmax(a, b);
  b = fmin(a, b);
  a = mx;
}

// merge own sorted-2 (k[0..1]) with partner's sorted-2 -> sorted-4 in k[0..3]
template <int CTRL, int RM>
__device__ __forceinline__ void merge_2to4_d(double k[8]) {
  int lo0 = DPP0(__double2loint(k[0]), CTRL, RM);
  int hi0 = DPP0(__double2hiint(k[0]), CTRL, RM);
  int lo1 = DPP0(__double2loint(k[1]), CTRL, RM);
  int hi1 = DPP0(__double2hiint(k[1]), CTRL, RM);
  double b0 = __hiloint2double(hi0, lo0);
  double b1 = __hiloint2double(hi1, lo1);
  double z2 = b1, z3 = b0; // bitonic: [k0,k1,b1,b0]
  ced(k[0], z2); ced(k[1], z3);
  ced(k[0], k[1]); ced(z2, z3);
  k[2] = z2; k[3] = z3;
}

// merge own sorted-4 (k[0..3]) with partner's sorted-4 -> sorted-8
template <int CTRL, int RM>
__device__ __forceinline__ void merge_first4(double k[8]) {
  double b[4];
#pragma unroll
  for (int i = 0; i < 4; i++) {
    int lo = DPP0(__double2loint(k[i]), CTRL, RM);
    int hi = DPP0(__double2hiint(k[i]), CTRL, RM);
    b[i] = __hiloint2double(hi, lo);
  }
  k[4] = b[3]; k[5] = b[2]; k[6] = b[1]; k[7] = b[0]; // bitonic sequence
  ced(k[0],k[4]); ced(k[1],k[5]); ced(k[2],k[6]); ced(k[3],k[7]);
  ced(k[0],k[2]); ced(k[1],k[3]); ced(k[4],k[6]); ced(k[5],k[7]);
  ced(k[0],k[1]); ced(k[2],k[3]); ced(k[4],k[5]); ced(k[6],k[7]);
}

// pull partner's sorted-8, keep top-8 of union, resort desc
template <int CTRL, int RM>
__device__ __forceinline__ void merge_level(double k[8]) {
  double b[8];
#pragma unroll
  for (int i = 0; i < 8; i++) {
    int lo = DPP0(__double2loint(k[i]), CTRL, RM);
    int hi = DPP0(__double2hiint(k[i]), CTRL, RM);
    b[i] = __hiloint2double(hi, lo);
  }
#pragma unroll
  for (int i = 0; i < 8; i++) k[i] = fmax(k[i], b[7 - i]);
  ced(k[0],k[4]); ced(k[1],k[5]); ced(k[2],k[6]); ced(k[3],k[7]);
  ced(k[0],k[2]); ced(k[1],k[3]); ced(k[4],k[6]); ced(k[5],k[7]);
  ced(k[0],k[1]); ced(k[2],k[3]); ced(k[4],k[5]); ced(k[6],k[7]);
}

// ---- f32 list network (for theta = 8th largest of 256 lane maxima) ----
__device__ __forceinline__ void cedf(float &a, float &b) {
  float mx = fmaxf(a, b);
  b = fminf(a, b);
  a = mx;
}
__device__ __forceinline__ void sort4f(float k[8]) {
  cedf(k[0],k[1]); cedf(k[2],k[3]);
  cedf(k[0],k[2]); cedf(k[1],k[3]);
  cedf(k[1],k[2]);
}
template <int CTRL, int RM>
__device__ __forceinline__ void merge_first4_f32(float k[8]) {
  float b[4];
#pragma unroll
  for (int i = 0; i < 4; i++)
    b[i] = __int_as_float(DPP0(__float_as_int(k[i]), CTRL, RM));
  k[4] = b[3]; k[5] = b[2]; k[6] = b[1]; k[7] = b[0];
  cedf(k[0],k[4]); cedf(k[1],k[5]); cedf(k[2],k[6]); cedf(k[3],k[7]);
  cedf(k[0],k[2]); cedf(k[1],k[3]); cedf(k[4],k[6]); cedf(k[5],k[7]);
  cedf(k[0],k[1]); cedf(k[2],k[3]); cedf(k[4],k[5]); cedf(k[6],k[7]);
}
template <int CTRL, int RM>
__device__ __forceinline__ void merge_level_f32(float k[8]) {
  float b[8];
#pragma unroll
  for (int i = 0; i < 8; i++)
    b[i] = __int_as_float(DPP0(__float_as_int(k[i]), CTRL, RM));
#pragma unroll
  for (int i = 0; i < 8; i++) k[i] = fmaxf(k[i], b[7 - i]);
  cedf(k[0],k[4]); cedf(k[1],k[5]); cedf(k[2],k[6]); cedf(k[3],k[7]);
  cedf(k[0],k[2]); cedf(k[1],k[3]); cedf(k[4],k[6]); cedf(k[5],k[7]);
  cedf(k[0],k[1]); cedf(k[2],k[3]); cedf(k[4],k[5]); cedf(k[6],k[7]);
}

#define FMAX_STAGE(x, ctrl, rm)                                                \
  x = fmaxf(x, __int_as_float(DPP0(__float_as_int(x), ctrl, rm)))
#define FADD_STAGE(x, ctrl, rm)                                                \
  x = x + __int_as_float(DPP0(__float_as_int(x), ctrl, rm))

__device__ __forceinline__ float wave_max_f32(float x) {
  FMAX_STAGE(x, 0x111, 0xf);
  FMAX_STAGE(x, 0x112, 0xf);
  FMAX_STAGE(x, 0x114, 0xf);
  FMAX_STAGE(x, 0x118, 0xf);
  FMAX_STAGE(x, 0x142, 0xa);
  FMAX_STAGE(x, 0x143, 0xc);
  return x; // lane 63 has the max
}
__device__ __forceinline__ float wave_sum_f32(float x) {
  FADD_STAGE(x, 0x111, 0xf);
  FADD_STAGE(x, 0x112, 0xf);
  FADD_STAGE(x, 0x114, 0xf);
  FADD_STAGE(x, 0x118, 0xf);
  FADD_STAGE(x, 0x142, 0xa);
  FADD_STAGE(x, 0x143, 0xc);
  return x; // lane 63 has the sum
}
__device__ __forceinline__ int rl63(int v) {
  return __builtin_amdgcn_readlane(v, 63);
}

__global__ void __launch_bounds__(NTHREADS)
me_fused(const float *__restrict__ x, const float *__restrict__ tape_re,
         const float *__restrict__ tape_im, const float *__restrict__ eta_param,
         const float *__restrict__ tbias_re, const float *__restrict__ tbias_im,
         float *__restrict__ out) {
  __shared__ float4 sc4[DIM_];                 // (h, vre, vim, 0)
  __shared__ float2 dxy[DIM_];                 // scatter deltas
  __shared__ float4 lmax4[NWORK / 4];          // 256 per-lane |c| maxima
  __shared__ unsigned long long cand_lds[CCAP];// candidate keys (f64 packed)
  __shared__ int ccnt;                         // candidate count
  __shared__ float red_sh[4];                  // norm^2 partials

  const int tid = threadIdx.x;
  const int lane = tid & 63;
  const int wid = tid >> 6;
  const int wtid = tid - 64; // worker element base (valid for wid>0)
  const int b = blockIdx.x;

  const float eta = fabsf(eta_param[0]);

  // worker state (unnormalized v; ivn applied per step)
  float vre[EPT], vim[EPT], tbre_[EPT], tbim_[EPT];
  float hcur[EPT], hnext[EPT], av[EPT];
  const float *xb = x + (size_t)b * TSTEPS * DIM_;

  if (wid > 0) {
    float acc = 0.f, lm = 0.f;
#pragma unroll
    for (int j = 0; j < EPT; j++) {
      int e = wtid + NWORK * j;
      float a = tape_re[e], c2 = tape_im[e];
      vre[j] = a; vim[j] = c2;
      tbre_[j] = tbias_re[e]; tbim_[j] = tbias_im[e];
      float h = xb[e];
      hcur[j] = h; hnext[j] = h;
      dxy[e] = make_float2(0.f, 0.f);
      acc += a * a + c2 * c2;
      // prep(0): scale-invariant key magnitude + staging
      float cr = h * a, ci = h * c2;
      av[j] = sqrtf(cr * cr + ci * ci);
      lm = fmaxf(lm, av[j]);
      sc4[e] = make_float4(h, a, c2, 0.f);
    }
    float ws = wave_sum_f32(acc);
    if (lane == 63) red_sh[wid - 1] = ws;
    ((float *)lmax4)[wtid] = lm;
  }
  if (tid == 0) ccnt = 0;

  // transient slots live in wave0 registers (lanes 0..15)
  int s_ti = 0, s_tj = 0, s_cnt = 0;
  float s_mre = 0.f, s_mim = 0.f;

  float osr[EPT], osi[EPT]; // workers: normalized s (pre-update), for patch

  __syncthreads(); // B3 equivalent for t=0

  for (int t = 0; t < TSTEPS; t++) {
    // per-step scalar: ivn = 1/max(||v||,1e-8)  (red_sh from prep/[C])
    float ivn;
    {
      float tot = (red_sh[0] + red_sh[1]) + (red_sh[2] + red_sh[3]);
      ivn = 1.f / fmaxf(sqrtf(tot), 1e-8f);
    }

    // ============ [A] workers: theta + candidate extraction ONLY ==========
    if (wid > 0) {
      // theta = 8th largest of the 256 per-lane maxima (f32 network)
      float4 q = lmax4[lane];
      float k[8];
      k[0] = q.x; k[1] = q.y; k[2] = q.z; k[3] = q.w;
      k[4] = 0.f; k[5] = 0.f; k[6] = 0.f; k[7] = 0.f;
      sort4f(k);
      merge_first4_f32<0x111, 0xf>(k);
      merge_level_f32<0x112, 0xf>(k);
      merge_level_f32<0x114, 0xf>(k);
      merge_level_f32<0x118, 0xf>(k);
      merge_level_f32<0x142, 0xa>(k);
      merge_level_f32<0x143, 0xc>(k);
      float th = __int_as_float(rl63(__float_as_int(k[7])));
      // extract candidates (guaranteed: 8 <= cnt; typically 8-16)
#pragma unroll
      for (int j = 0; j < EPT; j++) {
        if (av[j] >= th) {
          int e = wtid + NWORK * j;
          int slot = atomicAdd(&ccnt, 1);
          if (slot < CCAP)
            cand_lds[slot] = (unsigned long long)__double_as_longlong(
                __hiloint2double(__float_as_int(av[j]), ~e));
        }
      }
    }
    __syncthreads(); // B1: candidates ready

    // ==== [S] wave0 serial dynamics  ∥  workers: prefetch/out/spec ========
    if (wid == 0) {
      int cnt = ccnt;
      if (lane == 0) ccnt = 0; // reset (next append after B2+B3)
      if (cnt > CCAP) cnt = CCAP;
      // load 2 candidates per lane: slots 2*lane, 2*lane+1
      unsigned long long u0 = cand_lds[2 * lane];
      unsigned long long u1 = cand_lds[2 * lane + 1];
      double a = (2 * lane < cnt) ? __longlong_as_double((long long)u0) : 0.0;
      double b2 = (2 * lane + 1 < cnt) ? __longlong_as_double((long long)u1) : 0.0;
      double c[8];
      c[0] = fmax(a, b2); c[1] = fmin(a, b2);
      c[2] = 0.0; c[3] = 0.0; c[4] = 0.0; c[5] = 0.0; c[6] = 0.0; c[7] = 0.0;
      merge_2to4_d<0x111, 0xf>(c);  // sorted-4, lane1 covers slots 0-3
      merge_first4<0x112, 0xf>(c);  // lane3 covers slots 0-7
      int src = 3;
      if (cnt > 8)  { merge_level<0x114, 0xf>(c); src = 7;  }  // 0-15
      if (cnt > 16) { merge_level<0x118, 0xf>(c); src = 15; }  // 0-31
      if (cnt > 32) { merge_level<0x142, 0xa>(c); src = 31; }  // 0-63
      if (cnt > 64) { merge_level<0x143, 0xc>(c); src = 63; }  // 0-127
      int top[KTOP];
#pragma unroll
      for (int r = 0; r < KTOP; r++)
        top[r] = ~__builtin_amdgcn_readlane(__double2loint(c[r]), src);

      // ---- pair (ii,jj) for lane p, row-major triu order ----
      int pi = (lane < 28) ? lane : 27;
      int ii = 0, base = 0;
      if (pi >= 7)  { ii = 1; base = 7;  }
      if (pi >= 13) { ii = 2; base = 13; }
      if (pi >= 18) { ii = 3; base = 18; }
      if (pi >= 22) { ii = 4; base = 22; }
      if (pi >= 25) { ii = 5; base = 25; }
      if (pi >= 27) { ii = 6; base = 27; }
      int jj = ii + 1 + (pi - base);
      int gi = top[0];
      if (ii == 1) gi = top[1];
      if (ii == 2) gi = top[2];
      if (ii == 3) gi = top[3];
      if (ii == 4) gi = top[4];
      if (ii == 5) gi = top[5];
      if (ii == 6) gi = top[6];
      int gj = top[1];
      if (jj == 2) gj = top[2];
      if (jj == 3) gj = top[3];
      if (jj == 4) gj = top[4];
      if (jj == 5) gj = top[5];
      if (jj == 6) gj = top[6];
      if (jj == 7) gj = top[7];

      float4 c4i = sc4[gi], c4j = sc4[gj];
      float sri = c4i.y * ivn, sii2 = c4i.z * ivn;
      float srj = c4j.y * ivn, sij = c4j.z * ivn;
      float cri = c4i.x * sri, cii = c4i.x * sii2;
      float crj = c4j.x * srj, cij = c4j.x * sij;
      float score = cri * crj + cii * cij; // Re(c_i conj(c_j))
      bool valid = (lane < 28);
      bool pos = valid && (score > 0.f);
      unsigned long long posmask = __ballot(pos);
      int npos = __popcll(posmask);
      float pr = sri * srj - sii2 * sij;
      float pq = sri * sij + sii2 * srj;
      float ap = fmaxf(sqrtf(pr * pr + pq * pq), 1e-8f);
      float mr = (0.05f * pr) / ap, mi = (0.05f * pq) / ap;

      unsigned long long bmask = 0ull;
      if (npos > 0) {
        int nbind = (int)((float)npos * 0.15f);
        if (nbind < 1) nbind = 1;
        float val = pos ? score : -__builtin_inff();
        float th2 = 0.f;
        for (int k2 = 0; k2 < nbind; ++k2) {
          float mx = wave_max_f32(val);
          th2 = __int_as_float(rl63(__float_as_int(mx)));
          if (k2 + 1 < nbind) {
            unsigned long long em = __ballot(val == th2);
            if (lane == (int)__builtin_ctzll(em)) val = -__builtin_inff();
          }
        }
        bool bind = valid && (score >= th2);
        bmask = __ballot(bind);
      }
      // slot scan in pair order
      while (bmask) {
        int pp = (int)__builtin_ctzll(bmask);
        bmask &= bmask - 1;
        int pci = __builtin_amdgcn_readlane(gi, pp);
        int pcj = __builtin_amdgcn_readlane(gj, pp);
        int pmr = __builtin_amdgcn_readlane(__float_as_int(mr), pp);
        int pmi = __builtin_amdgcn_readlane(__float_as_int(mi), pp);
        bool isslot = (lane < MSLOT);
        bool match = isslot && (s_cnt > 0) &&
                     ((s_ti == pci && s_tj == pcj) ||
                      (s_ti == pcj && s_tj == pci));
        unsigned long long mm = __ballot(match);
        if (mm != 0ull) {
          if (lane == (int)__builtin_ctzll(mm)) s_cnt = 5; // refresh only
        } else {
          unsigned long long fm = __ballot(isslot && s_cnt <= 0);
          if (fm != 0ull && lane == (int)__builtin_ctzll(fm)) {
            s_ti = pci; s_tj = pcj;
            s_mre = __int_as_float(pmr); s_mim = __int_as_float(pmi);
            s_cnt = 5;
          }
        }
      }
      // decay + alive + scatter; dead slots add exact 0.0 -> skip atomics
      if (lane < MSLOT) {
        s_mre *= 0.9f; s_mim *= 0.9f; s_cnt -= 1;
        bool alive = (s_cnt > 0) &&
                     (sqrtf(s_mre * s_mre + s_mim * s_mim) > 1e-6f);
        if (!alive) { s_cnt = 0; s_mre = 0.f; s_mim = 0.f; }
        if (s_cnt > 0) {
          atomicAdd(&dxy[s_ti].x, 0.1f * s_mre);
          atomicAdd(&dxy[s_tj].x, 0.1f * s_mre);
          atomicAdd(&dxy[s_ti].y, 0.1f * s_mim);
          atomicAdd(&dxy[s_tj].y, 0.1f * s_mim);
        }
      }
    } else {
      // ============ workers overlap wave0's serial section ============
      if (t + 1 < TSTEPS) {
        const float *xr = xb + (size_t)(t + 1) * DIM_;
#pragma unroll
        for (int j = 0; j < EPT; j++) hnext[j] = xr[wtid + NWORK * j];
      }
      if (t > 0) {
        float *op = out + ((size_t)b * TSTEPS + (t - 1)) * DIM_;
#pragma unroll
        for (int j = 0; j < EPT; j++) {
          float sr = vre[j] * ivn, si = vim[j] * ivn;
          op[wtid + NWORK * j] = sqrtf(sr * sr + si * si);
        }
      }
      // speculative update with delta = 0 (exact for untouched elements)
#pragma unroll
      for (int j = 0; j < EPT; j++) {
        float sri = vre[j] * ivn, sii2 = vim[j] * ivn;
        osr[j] = sri; osi[j] = sii2;
        float h = hcur[j];
        float car = h * sri, cai = h * sii2;
        bool res = (car > 1e-6f) && (fabsf(cai) < car);
        bool tor = (car < -1e-6f) || (fabsf(cai) >= fabsf(car));
        float m1 = (res || tor) ? 1.f : 0.f;
        float mt = tor ? 1.f : 0.f;
        float ur = eta * (car * m1 + mt * tbre_[j]);
        float ui = eta * (cai * m1 + mt * tbim_[j]);
        vre[j] = sri + ur; vim[j] = sii2 + ui;
      }
    }
    __syncthreads(); // B2: dxy ready

    // ============ [C] workers: sparse patch + norm + prep(t+1) =============
    if (wid > 0) {
      float2 dd[EPT];
#pragma unroll
      for (int j = 0; j < EPT; j++) dd[j] = dxy[wtid + NWORK * j];
      float acc2 = 0.f, lm = 0.f;
#pragma unroll
      for (int j = 0; j < EPT; j++) {
        int e = wtid + NWORK * j;
        if (dd[j].x != 0.f || dd[j].y != 0.f) {
          dxy[e] = make_float2(0.f, 0.f); // re-zero touched
          float ar = osr[j] + dd[j].x, ai = osi[j] + dd[j].y;
          float h = hcur[j];
          float car = h * ar, cai = h * ai;
          bool res = (car > 1e-6f) && (fabsf(cai) < car);
          bool tor = (car < -1e-6f) || (fabsf(cai) >= fabsf(car));
          float m1 = (res || tor) ? 1.f : 0.f;
          float mt = tor ? 1.f : 0.f;
          float ur = eta * (car * m1 + mt * tbre_[j]);
          float ui = eta * (cai * m1 + mt * tbim_[j]);
          vre[j] = osr[j] + ur; vim[j] = osi[j] + ui;
        }
        acc2 += vre[j] * vre[j] + vim[j] * vim[j];
        // prep(t+1): advance h, compute |c| key magnitude, stage sc4
        float h = hnext[j];
        hcur[j] = h;
        float cr = h * vre[j], ci = h * vim[j];
        av[j] = sqrtf(cr * cr + ci * ci);
        lm = fmaxf(lm, av[j]);
        sc4[e] = make_float4(h, vre[j], vim[j], 0.f);
      }
      float ws = wave_sum_f32(acc2);
      if (lane == 63) red_sh[wid - 1] = ws;
      ((float *)lmax4)[wtid] = lm;
    }
    __syncthreads(); // B3: lmax/sc4/red_sh ready for t+1
  }

  // epilogue: final output row
  if (wid > 0) {
    float tot = (red_sh[0] + red_sh[1]) + (red_sh[2] + red_sh[3]);
    float ivnF = 1.f / fmaxf(sqrtf(tot), 1e-8f);
    float *op = out + ((size_t)b * TSTEPS + (TSTEPS - 1)) * DIM_;
#pragma unroll
    for (int j = 0; j < EPT; j++) {
      float sr = vre[j] * ivnF, si = vim[j] * ivnF;
      op[wtid + NWORK * j] = sqrtf(sr * sr + si * si);
    }
  }
}

extern "C" void kernel_launch(void *const *d_in, const int *in_sizes, int n_in,
                              void *d_out, int out_size, void *d_ws,
                              size_t ws_size, hipStream_t stream) {
  const float *x = (const float *)d_in[0];
  const float *tre = (const float *)d_in[1];
  const float *tim = (const float *)d_in[2];
  const float *eta = (const float *)d_in[3];
  const float *tbre = (const float *)d_in[4];
  const float *tbim = (const float *)d_in[5];
  float *out = (float *)d_out;
  me_fused<<<NB, NTHREADS, 0, stream>>>(x, tre, tim, eta, tbre, tbim, out);
}